// Round 1
// 951.265 us; speedup vs baseline: 3.5540x; 3.5540x over previous
//
#include <hip/hip_runtime.h>
#include <hip/hip_bf16.h>
#include <math.h>

// Problem constants
#define V 32000
#define S 256
#define B 16
#define E 32
#define H 16
#define INV_KEEP (1.0f / 0.6f)
#define MR (S * B)      // 4096 hcat rows (sb = t*16 + b)
#define NVT (V / 16)    // 2000 v-tiles of 16

typedef __bf16 bf16x8 __attribute__((ext_vector_type(8)));
typedef float  f32x4  __attribute__((ext_vector_type(4)));

// dtype-generic load/store helpers --------------------------------------------
static __device__ __forceinline__ float ldf(const float* p, int i) { return p[i]; }
static __device__ __forceinline__ float ldf(const __hip_bfloat16* p, int i) { return __bfloat162float(p[i]); }
static __device__ __forceinline__ void stf(float* p, size_t i, float v) { p[i] = v; }
static __device__ __forceinline__ void stf(__hip_bfloat16* p, size_t i, float v) { p[i] = __float2bfloat16(v); }

// ---------------------------------------------------------------------------
// K0: dtype detector (unchanged).
// ---------------------------------------------------------------------------
__global__ void detect_kernel(const unsigned int* __restrict__ emb_words,
                              int* __restrict__ flag) {
    int lane = threadIdx.x;
    unsigned int w = emb_words[lane];
    unsigned int lo = w & 0xFFFFu;
    unsigned int ab = lo & 0x7FFFu;
    int hit = (ab == 0u) || (ab >= 0x3000u && ab <= 0x3E80u);
    unsigned long long m = __ballot(hit != 0);
    if (lane == 0) flag[0] = (__popcll(m) >= 32) ? 1 : 0;
}

// ---------------------------------------------------------------------------
// K1: pre[dir][t][b][i] = b_ih[i] + sum_e emb[tok[t,b]][e] * W_ih[e][i] (unchanged)
// ---------------------------------------------------------------------------
template <typename T>
__global__ void precompute_kernel(const int* __restrict__ tok,
                                  const T* __restrict__ emb,
                                  const T* __restrict__ W_lr,
                                  const T* __restrict__ b_lr,
                                  const T* __restrict__ W_rl,
                                  const T* __restrict__ b_rl,
                                  float* __restrict__ pre,
                                  const int* __restrict__ flag, int want) {
    if (flag[0] != want) return;
    int id = blockIdx.x * blockDim.x + threadIdx.x;   // 2*S*B*H = 131072
    if (id >= 2 * S * B * H) return;
    int dir = id >> 16;
    int rem = id & 0xFFFF;
    int t = rem >> 8;
    int b = (rem >> 4) & 15;
    int i = rem & 15;
    const T* Wp = dir ? W_rl : W_lr;
    const T* bp = dir ? b_rl : b_lr;
    int tk = tok[t * B + b];
    const T* er = emb + (size_t)tk * E;
    float acc = ldf(bp, i);
#pragma unroll
    for (int e = 0; e < E; ++e)
        acc += ldf(er, e) * ldf(Wp, e * H + i);
    pre[id] = acc;
}

// ---------------------------------------------------------------------------
// K2: the sequential scans (unchanged).
// ---------------------------------------------------------------------------
template <typename T>
__global__ void scan_kernel(const float* __restrict__ pre,
                            const T* __restrict__ mask_lr,
                            const T* __restrict__ mask_rl,
                            const T* __restrict__ W_lr,
                            const T* __restrict__ W_rl,
                            const T* __restrict__ h0,
                            float* __restrict__ sarr,
                            const int* __restrict__ flag, int want) {
    if (flag[0] != want) return;
    int dir = blockIdx.x;
    int tid = threadIdx.x;     // 0..255
    int b = tid >> 4;
    int i = tid & 15;
    int lane = tid & 63;
    const T* Wp = dir ? W_rl : W_lr;
    const T* mk = dir ? mask_rl : mask_lr;
    float wh[H];
#pragma unroll
    for (int j = 0; j < H; ++j) wh[j] = ldf(Wp, (E + j) * H + i);
    float h = ldf(h0, i);
    const float* pred = pre + dir * (S * B * H);
    float* sd = sarr + dir * (S * B * H);
    for (int k = 0; k < S; ++k) {
        int t = dir ? (S - 1 - k) : k;
        int idx = t * 256 + b * 16 + i;
        float acc = pred[idx];
#pragma unroll
        for (int j = 0; j < H; ++j) {
            int src = (lane & ~15) | j;
            acc += __shfl(h, src, 64) * wh[j];
        }
        float hn = tanhf(acc);
        float m = ldf(mk, idx);
        h = hn * (m * INV_KEEP);
        sd[idx] = h;
    }
}

// ---------------------------------------------------------------------------
// K3: pack hcat rows into bf16 hi/lo split, MFMA A-frag friendly layout:
// hcb[row][k], row = t*16+b (0..4095), k = 0..31. Lane l of a wave later
// loads 8 contiguous k at (row = l&15, k0 = (l>>4)*8).
// ---------------------------------------------------------------------------
template <typename T>
__global__ void pack_kernel(const float* __restrict__ sarr,
                            const T* __restrict__ h0,
                            __bf16* __restrict__ hi,
                            __bf16* __restrict__ lo,
                            const int* __restrict__ flag, int want) {
    if (flag[0] != want) return;
    int id = blockIdx.x * blockDim.x + threadIdx.x;  // row*32 + k, 131072 total
    int k = id & 31;
    int row = id >> 5;
    int t = row >> 4, b = row & 15;
    const float* s0 = sarr;
    const float* s1 = sarr + S * B * H;
    float v;
    if (k < H)
        v = (t == 0) ? ldf(h0, k) : s0[(t - 1) * 256 + b * 16 + k];
    else
        v = (t == S - 1) ? ldf(h0, k - H) : s1[(t + 1) * 256 + b * 16 + (k - H)];
    __bf16 h = (__bf16)v;
    hi[id] = h;
    lo[id] = (__bf16)(v - (float)h);
}

__global__ void zero_kernel(float* __restrict__ se) {
    int i = blockIdx.x * 256 + threadIdx.x;
    if (i < MR) se[i] = 0.f;
}

// ---------------------------------------------------------------------------
// K4: sum-exp pass. Block = (sb-tile, v-chunk). Each wave: A-frag resident in
// regs, loops its v-tiles, 3 split-bf16 MFMAs per tile (fp32-accurate logits),
// exp+accumulate in regs, one shuffle-reduce + 16 atomicAdds at the end.
// ---------------------------------------------------------------------------
template <typename T>
__global__ __launch_bounds__(256) void lse_kernel(
        const __bf16* __restrict__ hi, const __bf16* __restrict__ lo,
        const T* __restrict__ W_ho, const T* __restrict__ b_ho,
        float* __restrict__ se,
        const int* __restrict__ flag, int want) {
    if (flag[0] != want) return;
    int sbt = blockIdx.x >> 3;        // 0..255
    int vch = blockIdx.x & 7;         // 0..7
    int wave = threadIdx.x >> 6;
    int l = threadIdx.x & 63;
    int c = l & 15, g = l >> 4;
    int aoff = (sbt * 16 + c) * 32 + g * 8;
    bf16x8 ah = *(const bf16x8*)(hi + aoff);
    bf16x8 al = *(const bf16x8*)(lo + aoff);
    float part[4] = {0.f, 0.f, 0.f, 0.f};
    int vt_end = (vch + 1) * (NVT / 8);
    for (int vt = vch * (NVT / 8) + wave; vt < vt_end; vt += 4) {
        int v0 = vt * 16;
        const T* wp = W_ho + (g * 8) * V + v0 + c;
        bf16x8 bh, bl;
#pragma unroll
        for (int j = 0; j < 8; ++j) {
            float w = ldf(wp, j * V);
            __bf16 wh = (__bf16)w;
            bh[j] = wh;
            bl[j] = (__bf16)(w - (float)wh);
        }
        f32x4 acc = {0.f, 0.f, 0.f, 0.f};
        acc = __builtin_amdgcn_mfma_f32_16x16x32_bf16(ah, bh, acc, 0, 0, 0);
        acc = __builtin_amdgcn_mfma_f32_16x16x32_bf16(al, bh, acc, 0, 0, 0);
        acc = __builtin_amdgcn_mfma_f32_16x16x32_bf16(ah, bl, acc, 0, 0, 0);
        float bb = ldf(b_ho, v0 + c);
#pragma unroll
        for (int r = 0; r < 4; ++r) part[r] += __expf(acc[r] + bb);
    }
#pragma unroll
    for (int r = 0; r < 4; ++r) {
        float p = part[r];
        p += __shfl_xor(p, 1, 64);
        p += __shfl_xor(p, 2, 64);
        p += __shfl_xor(p, 4, 64);
        p += __shfl_xor(p, 8, 64);
        if (c == 0) atomicAdd(&se[sbt * 16 + g * 4 + r], p);
    }
}

__global__ void log_kernel(float* __restrict__ se) {
    int i = blockIdx.x * 256 + threadIdx.x;
    if (i < MR) se[i] = logf(se[i]);
}

// ---------------------------------------------------------------------------
// K5: write pass. Single-wave blocks; block = (v-tile, sb-chunk). B-frag for
// the wave's 16 vocab columns is loaded ONCE and reused across 64 sb-tiles.
// ---------------------------------------------------------------------------
template <typename T>
__global__ __launch_bounds__(64) void write_kernel(
        const __bf16* __restrict__ hi, const __bf16* __restrict__ lo,
        const T* __restrict__ W_ho, const T* __restrict__ b_ho,
        const float* __restrict__ lse, T* __restrict__ out,
        const int* __restrict__ flag, int want) {
    if (flag[0] != want) return;
    int vt = blockIdx.x >> 2;   // 0..1999
    int sc = blockIdx.x & 3;    // sb-tile chunk of 64
    int l = threadIdx.x;
    int c = l & 15, g = l >> 4;
    int v0 = vt * 16;
    const T* wp = W_ho + (g * 8) * V + v0 + c;
    bf16x8 bh, bl;
#pragma unroll
    for (int j = 0; j < 8; ++j) {
        float w = ldf(wp, j * V);
        __bf16 wh = (__bf16)w;
        bh[j] = wh;
        bl[j] = (__bf16)(w - (float)wh);
    }
    float bb = ldf(b_ho, v0 + c);
    int sb_end = sc * 64 + 64;
    for (int sbt = sc * 64; sbt < sb_end; ++sbt) {
        int aoff = (sbt * 16 + c) * 32 + g * 8;
        bf16x8 ah = *(const bf16x8*)(hi + aoff);
        bf16x8 al = *(const bf16x8*)(lo + aoff);
        f32x4 acc = {0.f, 0.f, 0.f, 0.f};
        acc = __builtin_amdgcn_mfma_f32_16x16x32_bf16(ah, bh, acc, 0, 0, 0);
        acc = __builtin_amdgcn_mfma_f32_16x16x32_bf16(al, bh, acc, 0, 0, 0);
        acc = __builtin_amdgcn_mfma_f32_16x16x32_bf16(ah, bl, acc, 0, 0, 0);
#pragma unroll
        for (int r = 0; r < 4; ++r) {
            int row = sbt * 16 + g * 4 + r;
            stf(out, (size_t)row * V + v0 + c, acc[r] + bb - lse[row]);
        }
    }
}

// ---------------------------------------------------------------------------
// Workspace layout (floats), identical 1MB+4B footprint to the proven kernel:
//   [0      .. 131072)  pre   -> reused as hcb_hi (256KB) + hcb_lo (256KB)
//   [131072 .. 262144)  sarr  -> first 4096 floats reused as sumexp/lse
//   byte offset 1MB: flag
// Ordering makes every alias safe: pack reads sarr AFTER scan, writes the
// (dead) pre region; zero/log touch sarr head AFTER pack has read sarr.
// All dtype-variant kernels are flag-gated, so the inactive variant never
// writes anything.
// ---------------------------------------------------------------------------
extern "C" void kernel_launch(void* const* d_in, const int* in_sizes, int n_in,
                              void* d_out, int out_size, void* d_ws, size_t ws_size,
                              hipStream_t stream) {
    const int* tok = (const int*)d_in[0];

    float* ws     = (float*)d_ws;
    float* pre    = ws;                       // 512 KB
    float* sarr   = ws + 2 * S * B * H;       // 512 KB
    __bf16* hcb_hi = (__bf16*)ws;             // aliases pre, 256 KB
    __bf16* hcb_lo = (__bf16*)(ws + 65536);   // aliases pre, 256 KB
    float* se     = sarr;                     // 16 KB, aliases sarr head
    int*   flag   = (int*)((char*)d_ws + (size_t)4 * 2 * 2 * S * B * H);  // +1 MB

    detect_kernel<<<1, 64, 0, stream>>>((const unsigned int*)d_in[3], flag);

    // fp32 variant (want=0)
    {
        const float* mask_lr = (const float*)d_in[1];
        const float* mask_rl = (const float*)d_in[2];
        const float* emb     = (const float*)d_in[3];
        const float* W_lr    = (const float*)d_in[4];
        const float* b_lr    = (const float*)d_in[5];
        const float* W_rl    = (const float*)d_in[6];
        const float* b_rl    = (const float*)d_in[7];
        const float* h0      = (const float*)d_in[10];
        precompute_kernel<float><<<512, 256, 0, stream>>>(tok, emb, W_lr, b_lr, W_rl, b_rl, pre, flag, 0);
        scan_kernel<float><<<2, 256, 0, stream>>>(pre, mask_lr, mask_rl, W_lr, W_rl, h0, sarr, flag, 0);
        pack_kernel<float><<<512, 256, 0, stream>>>(sarr, h0, hcb_hi, hcb_lo, flag, 0);
    }

    // bf16 variant (want=1)
    {
        const __hip_bfloat16* mask_lr = (const __hip_bfloat16*)d_in[1];
        const __hip_bfloat16* mask_rl = (const __hip_bfloat16*)d_in[2];
        const __hip_bfloat16* emb     = (const __hip_bfloat16*)d_in[3];
        const __hip_bfloat16* W_lr    = (const __hip_bfloat16*)d_in[4];
        const __hip_bfloat16* b_lr    = (const __hip_bfloat16*)d_in[5];
        const __hip_bfloat16* W_rl    = (const __hip_bfloat16*)d_in[6];
        const __hip_bfloat16* b_rl    = (const __hip_bfloat16*)d_in[7];
        const __hip_bfloat16* h0      = (const __hip_bfloat16*)d_in[10];
        precompute_kernel<__hip_bfloat16><<<512, 256, 0, stream>>>(tok, emb, W_lr, b_lr, W_rl, b_rl, pre, flag, 1);
        scan_kernel<__hip_bfloat16><<<2, 256, 0, stream>>>(pre, mask_lr, mask_rl, W_lr, W_rl, h0, sarr, flag, 1);
        pack_kernel<__hip_bfloat16><<<512, 256, 0, stream>>>(sarr, h0, hcb_hi, hcb_lo, flag, 1);
    }

    zero_kernel<<<16, 256, 0, stream>>>(se);

    // sum-exp pass
    {
        const float* W_ho = (const float*)d_in[8];
        const float* b_ho = (const float*)d_in[9];
        lse_kernel<float><<<2048, 256, 0, stream>>>(hcb_hi, hcb_lo, W_ho, b_ho, se, flag, 0);
    }
    {
        const __hip_bfloat16* W_ho = (const __hip_bfloat16*)d_in[8];
        const __hip_bfloat16* b_ho = (const __hip_bfloat16*)d_in[9];
        lse_kernel<__hip_bfloat16><<<2048, 256, 0, stream>>>(hcb_hi, hcb_lo, W_ho, b_ho, se, flag, 1);
    }

    log_kernel<<<16, 256, 0, stream>>>(se);

    // write pass
    {
        const float* W_ho = (const float*)d_in[8];
        const float* b_ho = (const float*)d_in[9];
        write_kernel<float><<<8000, 64, 0, stream>>>(hcb_hi, hcb_lo, W_ho, b_ho, se, (float*)d_out, flag, 0);
    }
    {
        const __hip_bfloat16* W_ho = (const __hip_bfloat16*)d_in[8];
        const __hip_bfloat16* b_ho = (const __hip_bfloat16*)d_in[9];
        write_kernel<__hip_bfloat16><<<8000, 64, 0, stream>>>(hcb_hi, hcb_lo, W_ho, b_ho, se, (__hip_bfloat16*)d_out, flag, 1);
    }
}

// Round 3
// 848.412 us; speedup vs baseline: 3.9849x; 1.1212x over previous
//
#include <hip/hip_runtime.h>
#include <hip/hip_bf16.h>
#include <math.h>

// Problem constants
#define V 32000
#define S 256
#define B 16
#define E 32
#define H 16
#define INV_KEEP (1.0f / 0.6f)
#define MR (S * B)      // 4096 hcat rows (sb = t*16 + b)
#define NVT (V / 16)    // 2000 v-tiles of 16

typedef __bf16 bf16x8 __attribute__((ext_vector_type(8)));
typedef float  f32x4  __attribute__((ext_vector_type(4)));

// dtype-generic load/store helpers --------------------------------------------
static __device__ __forceinline__ float ldf(const float* p, int i) { return p[i]; }
static __device__ __forceinline__ float ldf(const __hip_bfloat16* p, int i) { return __bfloat162float(p[i]); }
static __device__ __forceinline__ void stf(float* p, size_t i, float v) { p[i] = v; }
static __device__ __forceinline__ void stf(__hip_bfloat16* p, size_t i, float v) { p[i] = __float2bfloat16(v); }

// ---------------------------------------------------------------------------
// K0: dtype detector (unchanged).
// ---------------------------------------------------------------------------
__global__ void detect_kernel(const unsigned int* __restrict__ emb_words,
                              int* __restrict__ flag) {
    int lane = threadIdx.x;
    unsigned int w = emb_words[lane];
    unsigned int lo = w & 0xFFFFu;
    unsigned int ab = lo & 0x7FFFu;
    int hit = (ab == 0u) || (ab >= 0x3000u && ab <= 0x3E80u);
    unsigned long long m = __ballot(hit != 0);
    if (lane == 0) flag[0] = (__popcll(m) >= 32) ? 1 : 0;
}

// ---------------------------------------------------------------------------
// K1: pre[dir][t][b][i] = b_ih[i] + sum_e emb[tok[t,b]][e] * W_ih[e][i] (unchanged)
// ---------------------------------------------------------------------------
template <typename T>
__global__ void precompute_kernel(const int* __restrict__ tok,
                                  const T* __restrict__ emb,
                                  const T* __restrict__ W_lr,
                                  const T* __restrict__ b_lr,
                                  const T* __restrict__ W_rl,
                                  const T* __restrict__ b_rl,
                                  float* __restrict__ pre,
                                  const int* __restrict__ flag, int want) {
    if (flag[0] != want) return;
    int id = blockIdx.x * blockDim.x + threadIdx.x;   // 2*S*B*H = 131072
    if (id >= 2 * S * B * H) return;
    int dir = id >> 16;
    int rem = id & 0xFFFF;
    int t = rem >> 8;
    int b = (rem >> 4) & 15;
    int i = rem & 15;
    const T* Wp = dir ? W_rl : W_lr;
    const T* bp = dir ? b_rl : b_lr;
    int tk = tok[t * B + b];
    const T* er = emb + (size_t)tk * E;
    float acc = ldf(bp, i);
#pragma unroll
    for (int e = 0; e < E; ++e)
        acc += ldf(er, e) * ldf(Wp, e * H + i);
    pre[id] = acc;
}

// ---------------------------------------------------------------------------
// K2: sequential scans.
//  - distance-2 register prefetch of pre/mask (only 8 waves exist; no TLP)
//  - tanh via v_exp identity (|acc| <= ~9 analytically, clamp to +-15 anyway)
//  - ds_swizzle group-broadcast with template-constant pattern (builtin
//    requires an ICE offset operand -> template<int J>, NOT a runtime param)
//  - 4-way split dot: dependent-FMA chain 16 -> ~6
// ---------------------------------------------------------------------------
template <int J>
static __device__ __forceinline__ float grp_bcast(float h) {
#if __has_builtin(__builtin_amdgcn_ds_swizzle)
    // BitMode: offset = (xor<<10)|(or<<5)|and; lane' = (lane & 0x10) | J
    return __uint_as_float(__builtin_amdgcn_ds_swizzle(
        __float_as_uint(h), (J << 5) | 0x10));
#else
    int lane = threadIdx.x & 63;
    return __shfl(h, (lane & ~15) | J, 64);
#endif
}
static __device__ __forceinline__ float fast_rcp(float x) {
#if __has_builtin(__builtin_amdgcn_rcpf)
    return __builtin_amdgcn_rcpf(x);
#else
    return 1.f / x;
#endif
}
static __device__ __forceinline__ float fast_tanh(float x) {
    x = fminf(fmaxf(x, -15.f), 15.f);
    float e = __expf(2.f * x);
    return 1.f - 2.f * fast_rcp(e + 1.f);
}

template <typename T>
__global__ void scan_kernel(const float* __restrict__ pre,
                            const T* __restrict__ mask_lr,
                            const T* __restrict__ mask_rl,
                            const T* __restrict__ W_lr,
                            const T* __restrict__ W_rl,
                            const T* __restrict__ h0,
                            float* __restrict__ sarr,
                            const int* __restrict__ flag, int want) {
    if (flag[0] != want) return;
    int dir = blockIdx.x;
    int tid = threadIdx.x;     // 0..255
    int b = tid >> 4;
    int i = tid & 15;
    const T* Wp = dir ? W_rl : W_lr;
    const T* mk = dir ? mask_rl : mask_lr;
    float wh[H];
#pragma unroll
    for (int j = 0; j < H; ++j) wh[j] = ldf(Wp, (E + j) * H + i);
    float h = ldf(h0, i);
    const float* pred = pre + dir * (S * B * H);
    float* sd = sarr + dir * (S * B * H);

    int base = b * 16 + i;
    int step = dir ? -256 : 256;
    int idx = (dir ? (S - 1) * 256 : 0) + base;

    float pA = pred[idx];
    float mA = ldf(mk, idx) * INV_KEEP;
    float pB = pred[idx + step];
    float mB = ldf(mk, idx + step) * INV_KEEP;

    for (int k = 0; k < S; ++k) {
        float pN = 0.f, mN = 0.f;
        if (k + 2 < S) {
            int idn = idx + 2 * step;
            pN = pred[idn];
            mN = ldf(mk, idn) * INV_KEEP;
        }
        float s0 = grp_bcast<0>(h) * wh[0];
        s0 += grp_bcast<1>(h) * wh[1];
        s0 += grp_bcast<2>(h) * wh[2];
        s0 += grp_bcast<3>(h) * wh[3];
        float s1 = grp_bcast<4>(h) * wh[4];
        s1 += grp_bcast<5>(h) * wh[5];
        s1 += grp_bcast<6>(h) * wh[6];
        s1 += grp_bcast<7>(h) * wh[7];
        float s2 = grp_bcast<8>(h) * wh[8];
        s2 += grp_bcast<9>(h) * wh[9];
        s2 += grp_bcast<10>(h) * wh[10];
        s2 += grp_bcast<11>(h) * wh[11];
        float s3 = grp_bcast<12>(h) * wh[12];
        s3 += grp_bcast<13>(h) * wh[13];
        s3 += grp_bcast<14>(h) * wh[14];
        s3 += grp_bcast<15>(h) * wh[15];
        float acc = pA + ((s0 + s1) + (s2 + s3));
        h = fast_tanh(acc) * mA;
        sd[idx] = h;
        pA = pB; mA = mB; pB = pN; mB = mN;
        idx += step;
    }
}

// ---------------------------------------------------------------------------
// K3: pack hcat rows into bf16 hi/lo split, MFMA A-frag friendly layout:
// hcb[row][k], row = t*16+b (0..4095), k = 0..31. Lane l of a wave later
// loads 8 contiguous k at (row = l&15, k0 = (l>>4)*8).
// ---------------------------------------------------------------------------
template <typename T>
__global__ void pack_kernel(const float* __restrict__ sarr,
                            const T* __restrict__ h0,
                            __bf16* __restrict__ hi,
                            __bf16* __restrict__ lo,
                            const int* __restrict__ flag, int want) {
    if (flag[0] != want) return;
    int id = blockIdx.x * blockDim.x + threadIdx.x;  // row*32 + k, 131072 total
    int k = id & 31;
    int row = id >> 5;
    int t = row >> 4, b = row & 15;
    const float* s0 = sarr;
    const float* s1 = sarr + S * B * H;
    float v;
    if (k < H)
        v = (t == 0) ? ldf(h0, k) : s0[(t - 1) * 256 + b * 16 + k];
    else
        v = (t == S - 1) ? ldf(h0, k - H) : s1[(t + 1) * 256 + b * 16 + (k - H)];
    __bf16 h = (__bf16)v;
    hi[id] = h;
    lo[id] = (__bf16)(v - (float)h);
}

__global__ void zero_kernel(float* __restrict__ se) {
    int i = blockIdx.x * 256 + threadIdx.x;
    if (i < MR) se[i] = 0.f;
}

// ---------------------------------------------------------------------------
// K3b: pre-pack W_ho into MFMA-B-fragment-major bf16 hi/lo planes + fp32 bias.
// Layout: wph[((vt*4 + g)*16 + c)*8 + j] = hi(W_ho[(g*8+j)*V + vt*16+c]).
// A wave's lane (c,g) later loads its whole B-fragment as two 16B loads.
// Total 2+2 MB (+128KB bias) -> L2 resident for lse/write.
// ---------------------------------------------------------------------------
template <typename T>
__global__ void wpack_kernel(const T* __restrict__ W_ho,
                             const T* __restrict__ b_ho,
                             __bf16* __restrict__ wph,
                             __bf16* __restrict__ wpl,
                             float* __restrict__ bsf,
                             const int* __restrict__ flag, int want) {
    if (flag[0] != want) return;
    int id = blockIdx.x * blockDim.x + threadIdx.x;  // 160000 total
    if (id < NVT * 64) {
        int c = id & 15, g = (id >> 4) & 3, vt = id >> 6;
        int v = vt * 16 + c;
        bf16x8 h8, l8;
#pragma unroll
        for (int j = 0; j < 8; ++j) {
            float w = ldf(W_ho, (size_t)(g * 8 + j) * V + v);
            __bf16 wh = (__bf16)w;
            h8[j] = wh;
            l8[j] = (__bf16)(w - (float)wh);
        }
        *(bf16x8*)(wph + (size_t)id * 8) = h8;
        *(bf16x8*)(wpl + (size_t)id * 8) = l8;
    } else {
        int v = id - NVT * 64;
        if (v < V) bsf[v] = ldf(b_ho, v);
    }
}

// ---------------------------------------------------------------------------
// K4p: sum-exp pass, packed-W version (dtype-free -> launched ONCE).
// ---------------------------------------------------------------------------
__global__ __launch_bounds__(256) void lse_packed_kernel(
        const __bf16* __restrict__ hi, const __bf16* __restrict__ lo,
        const __bf16* __restrict__ wph, const __bf16* __restrict__ wpl,
        const float* __restrict__ bsf,
        float* __restrict__ se) {
    int sbt = blockIdx.x >> 3;        // 0..255
    int vch = blockIdx.x & 7;         // 0..7
    int wave = threadIdx.x >> 6;
    int l = threadIdx.x & 63;
    int c = l & 15, g = l >> 4;
    int aoff = (sbt * 16 + c) * 32 + g * 8;
    bf16x8 ah = *(const bf16x8*)(hi + aoff);
    bf16x8 al = *(const bf16x8*)(lo + aoff);
    float part[4] = {0.f, 0.f, 0.f, 0.f};
    int vt_end = (vch + 1) * (NVT / 8);
    for (int vt = vch * (NVT / 8) + wave; vt < vt_end; vt += 4) {
        int woff = ((vt * 4 + g) * 16 + c) * 8;
        bf16x8 bh = *(const bf16x8*)(wph + woff);
        bf16x8 bl = *(const bf16x8*)(wpl + woff);
        f32x4 acc = {0.f, 0.f, 0.f, 0.f};
        acc = __builtin_amdgcn_mfma_f32_16x16x32_bf16(ah, bh, acc, 0, 0, 0);
        acc = __builtin_amdgcn_mfma_f32_16x16x32_bf16(al, bh, acc, 0, 0, 0);
        acc = __builtin_amdgcn_mfma_f32_16x16x32_bf16(ah, bl, acc, 0, 0, 0);
        float bb = bsf[vt * 16 + c];
#pragma unroll
        for (int r = 0; r < 4; ++r) part[r] += __expf(acc[r] + bb);
    }
#pragma unroll
    for (int r = 0; r < 4; ++r) {
        float p = part[r];
        p += __shfl_xor(p, 1, 64);
        p += __shfl_xor(p, 2, 64);
        p += __shfl_xor(p, 4, 64);
        p += __shfl_xor(p, 8, 64);
        if (c == 0) atomicAdd(&se[sbt * 16 + g * 4 + r], p);
    }
}

__global__ void log_kernel(float* __restrict__ se) {
    int i = blockIdx.x * 256 + threadIdx.x;
    if (i < MR) se[i] = logf(se[i]);
}

// ---------------------------------------------------------------------------
// K5p: write pass, packed-W version. B-frag loaded once per block (2x16B),
// reused across 64 sb-tiles.
// ---------------------------------------------------------------------------
template <typename T>
__global__ __launch_bounds__(64) void write_packed_kernel(
        const __bf16* __restrict__ hi, const __bf16* __restrict__ lo,
        const __bf16* __restrict__ wph, const __bf16* __restrict__ wpl,
        const float* __restrict__ bsf,
        const float* __restrict__ lse, T* __restrict__ out,
        const int* __restrict__ flag, int want) {
    if (flag[0] != want) return;
    int vt = blockIdx.x >> 2;   // 0..1999
    int sc = blockIdx.x & 3;    // sb-tile chunk of 64
    int l = threadIdx.x;
    int c = l & 15, g = l >> 4;
    int v0 = vt * 16;
    int woff = ((vt * 4 + g) * 16 + c) * 8;
    bf16x8 bh = *(const bf16x8*)(wph + woff);
    bf16x8 bl = *(const bf16x8*)(wpl + woff);
    float bb = bsf[v0 + c];
    int sb_end = sc * 64 + 64;
    for (int sbt = sc * 64; sbt < sb_end; ++sbt) {
        int aoff = (sbt * 16 + c) * 32 + g * 8;
        bf16x8 ah = *(const bf16x8*)(hi + aoff);
        bf16x8 al = *(const bf16x8*)(lo + aoff);
        f32x4 acc = {0.f, 0.f, 0.f, 0.f};
        acc = __builtin_amdgcn_mfma_f32_16x16x32_bf16(ah, bh, acc, 0, 0, 0);
        acc = __builtin_amdgcn_mfma_f32_16x16x32_bf16(al, bh, acc, 0, 0, 0);
        acc = __builtin_amdgcn_mfma_f32_16x16x32_bf16(ah, bl, acc, 0, 0, 0);
#pragma unroll
        for (int r = 0; r < 4; ++r) {
            int row = sbt * 16 + g * 4 + r;
            stf(out, (size_t)row * V + v0 + c, acc[r] + bb - lse[row]);
        }
    }
}

// ---------------------------------------------------------------------------
// Fallback (ws too small for packed W): round-1-proven lse/write.
// ---------------------------------------------------------------------------
template <typename T>
__global__ __launch_bounds__(256) void lse_kernel(
        const __bf16* __restrict__ hi, const __bf16* __restrict__ lo,
        const T* __restrict__ W_ho, const T* __restrict__ b_ho,
        float* __restrict__ se,
        const int* __restrict__ flag, int want) {
    if (flag[0] != want) return;
    int sbt = blockIdx.x >> 3;
    int vch = blockIdx.x & 7;
    int wave = threadIdx.x >> 6;
    int l = threadIdx.x & 63;
    int c = l & 15, g = l >> 4;
    int aoff = (sbt * 16 + c) * 32 + g * 8;
    bf16x8 ah = *(const bf16x8*)(hi + aoff);
    bf16x8 al = *(const bf16x8*)(lo + aoff);
    float part[4] = {0.f, 0.f, 0.f, 0.f};
    int vt_end = (vch + 1) * (NVT / 8);
    for (int vt = vch * (NVT / 8) + wave; vt < vt_end; vt += 4) {
        int v0 = vt * 16;
        const T* wp = W_ho + (g * 8) * V + v0 + c;
        bf16x8 bh, bl;
#pragma unroll
        for (int j = 0; j < 8; ++j) {
            float w = ldf(wp, j * V);
            __bf16 wh = (__bf16)w;
            bh[j] = wh;
            bl[j] = (__bf16)(w - (float)wh);
        }
        f32x4 acc = {0.f, 0.f, 0.f, 0.f};
        acc = __builtin_amdgcn_mfma_f32_16x16x32_bf16(ah, bh, acc, 0, 0, 0);
        acc = __builtin_amdgcn_mfma_f32_16x16x32_bf16(al, bh, acc, 0, 0, 0);
        acc = __builtin_amdgcn_mfma_f32_16x16x32_bf16(ah, bl, acc, 0, 0, 0);
        float bb = ldf(b_ho, v0 + c);
#pragma unroll
        for (int r = 0; r < 4; ++r) part[r] += __expf(acc[r] + bb);
    }
#pragma unroll
    for (int r = 0; r < 4; ++r) {
        float p = part[r];
        p += __shfl_xor(p, 1, 64);
        p += __shfl_xor(p, 2, 64);
        p += __shfl_xor(p, 4, 64);
        p += __shfl_xor(p, 8, 64);
        if (c == 0) atomicAdd(&se[sbt * 16 + g * 4 + r], p);
    }
}

template <typename T>
__global__ __launch_bounds__(64) void write_kernel(
        const __bf16* __restrict__ hi, const __bf16* __restrict__ lo,
        const T* __restrict__ W_ho, const T* __restrict__ b_ho,
        const float* __restrict__ lse, T* __restrict__ out,
        const int* __restrict__ flag, int want) {
    if (flag[0] != want) return;
    int vt = blockIdx.x >> 2;
    int sc = blockIdx.x & 3;
    int l = threadIdx.x;
    int c = l & 15, g = l >> 4;
    int v0 = vt * 16;
    const T* wp = W_ho + (g * 8) * V + v0 + c;
    bf16x8 bh, bl;
#pragma unroll
    for (int j = 0; j < 8; ++j) {
        float w = ldf(wp, j * V);
        __bf16 wh = (__bf16)w;
        bh[j] = wh;
        bl[j] = (__bf16)(w - (float)wh);
    }
    float bb = ldf(b_ho, v0 + c);
    int sb_end = sc * 64 + 64;
    for (int sbt = sc * 64; sbt < sb_end; ++sbt) {
        int aoff = (sbt * 16 + c) * 32 + g * 8;
        bf16x8 ah = *(const bf16x8*)(hi + aoff);
        bf16x8 al = *(const bf16x8*)(lo + aoff);
        f32x4 acc = {0.f, 0.f, 0.f, 0.f};
        acc = __builtin_amdgcn_mfma_f32_16x16x32_bf16(ah, bh, acc, 0, 0, 0);
        acc = __builtin_amdgcn_mfma_f32_16x16x32_bf16(al, bh, acc, 0, 0, 0);
        acc = __builtin_amdgcn_mfma_f32_16x16x32_bf16(ah, bl, acc, 0, 0, 0);
#pragma unroll
        for (int r = 0; r < 4; ++r) {
            int row = sbt * 16 + g * 4 + r;
            stf(out, (size_t)row * V + v0 + c, acc[r] + bb - lse[row]);
        }
    }
}

// ---------------------------------------------------------------------------
// Workspace layout (bytes):
//   [0      .. 512K)   pre (fp32) -> reused as hcb_hi (256K) + hcb_lo (256K)
//   [512K   .. 1M)     sarr (fp32); head 16K reused as sumexp/lse
//   [1M]               flag
//   -- packed path only (requires ws_size >= 8MB) --
//   [2M     .. 2M+2,048,000)  wph
//   [4M     .. 4M+2,048,000)  wpl
//   [6M     .. 6M+128K)       bsf (fp32 bias)
// Ordering keeps every alias safe: pack reads sarr AFTER scan, writes the
// dead pre region; zero/log touch sarr head AFTER pack has read sarr.
// ---------------------------------------------------------------------------
extern "C" void kernel_launch(void* const* d_in, const int* in_sizes, int n_in,
                              void* d_out, int out_size, void* d_ws, size_t ws_size,
                              hipStream_t stream) {
    const int* tok = (const int*)d_in[0];

    char* wsb      = (char*)d_ws;
    float* pre     = (float*)wsb;
    float* sarr    = (float*)(wsb + (512u << 10));
    __bf16* hcb_hi = (__bf16*)wsb;
    __bf16* hcb_lo = (__bf16*)(wsb + (256u << 10));
    float* se      = sarr;
    int*   flag    = (int*)(wsb + (1u << 20));
    __bf16* wph    = (__bf16*)(wsb + (2u << 20));
    __bf16* wpl    = (__bf16*)(wsb + (4u << 20));
    float* bsf     = (float*)(wsb + (6u << 20));
    const bool packed = ws_size >= ((size_t)8u << 20);

    detect_kernel<<<1, 64, 0, stream>>>((const unsigned int*)d_in[3], flag);

    if (packed) {
        wpack_kernel<float><<<625, 256, 0, stream>>>(
            (const float*)d_in[8], (const float*)d_in[9], wph, wpl, bsf, flag, 0);
        wpack_kernel<__hip_bfloat16><<<625, 256, 0, stream>>>(
            (const __hip_bfloat16*)d_in[8], (const __hip_bfloat16*)d_in[9], wph, wpl, bsf, flag, 1);
    }

    // fp32 variant (want=0)
    {
        const float* mask_lr = (const float*)d_in[1];
        const float* mask_rl = (const float*)d_in[2];
        const float* emb     = (const float*)d_in[3];
        const float* W_lr    = (const float*)d_in[4];
        const float* b_lr    = (const float*)d_in[5];
        const float* W_rl    = (const float*)d_in[6];
        const float* b_rl    = (const float*)d_in[7];
        const float* h0      = (const float*)d_in[10];
        precompute_kernel<float><<<512, 256, 0, stream>>>(tok, emb, W_lr, b_lr, W_rl, b_rl, pre, flag, 0);
        scan_kernel<float><<<2, 256, 0, stream>>>(pre, mask_lr, mask_rl, W_lr, W_rl, h0, sarr, flag, 0);
        pack_kernel<float><<<512, 256, 0, stream>>>(sarr, h0, hcb_hi, hcb_lo, flag, 0);
    }

    // bf16 variant (want=1)
    {
        const __hip_bfloat16* mask_lr = (const __hip_bfloat16*)d_in[1];
        const __hip_bfloat16* mask_rl = (const __hip_bfloat16*)d_in[2];
        const __hip_bfloat16* emb     = (const __hip_bfloat16*)d_in[3];
        const __hip_bfloat16* W_lr    = (const __hip_bfloat16*)d_in[4];
        const __hip_bfloat16* b_lr    = (const __hip_bfloat16*)d_in[5];
        const __hip_bfloat16* W_rl    = (const __hip_bfloat16*)d_in[6];
        const __hip_bfloat16* b_rl    = (const __hip_bfloat16*)d_in[7];
        const __hip_bfloat16* h0      = (const __hip_bfloat16*)d_in[10];
        precompute_kernel<__hip_bfloat16><<<512, 256, 0, stream>>>(tok, emb, W_lr, b_lr, W_rl, b_rl, pre, flag, 1);
        scan_kernel<__hip_bfloat16><<<2, 256, 0, stream>>>(pre, mask_lr, mask_rl, W_lr, W_rl, h0, sarr, flag, 1);
        pack_kernel<__hip_bfloat16><<<512, 256, 0, stream>>>(sarr, h0, hcb_hi, hcb_lo, flag, 1);
    }

    zero_kernel<<<16, 256, 0, stream>>>(se);

    if (packed) {
        lse_packed_kernel<<<2048, 256, 0, stream>>>(hcb_hi, hcb_lo, wph, wpl, bsf, se);
        log_kernel<<<16, 256, 0, stream>>>(se);
        write_packed_kernel<float><<<8000, 64, 0, stream>>>(
            hcb_hi, hcb_lo, wph, wpl, bsf, se, (float*)d_out, flag, 0);
        write_packed_kernel<__hip_bfloat16><<<8000, 64, 0, stream>>>(
            hcb_hi, hcb_lo, wph, wpl, bsf, se, (__hip_bfloat16*)d_out, flag, 1);
    } else {
        lse_kernel<float><<<2048, 256, 0, stream>>>(
            hcb_hi, hcb_lo, (const float*)d_in[8], (const float*)d_in[9], se, flag, 0);
        lse_kernel<__hip_bfloat16><<<2048, 256, 0, stream>>>(
            hcb_hi, hcb_lo, (const __hip_bfloat16*)d_in[8], (const __hip_bfloat16*)d_in[9], se, flag, 1);
        log_kernel<<<16, 256, 0, stream>>>(se);
        write_kernel<float><<<8000, 64, 0, stream>>>(
            hcb_hi, hcb_lo, (const float*)d_in[8], (const float*)d_in[9], se, (float*)d_out, flag, 0);
        write_kernel<__hip_bfloat16><<<8000, 64, 0, stream>>>(
            hcb_hi, hcb_lo, (const __hip_bfloat16*)d_in[8], (const __hip_bfloat16*)d_in[9], se, (__hip_bfloat16*)d_out, flag, 1);
    }
}

// Round 4
// 733.387 us; speedup vs baseline: 4.6098x; 1.1568x over previous
//
#include <hip/hip_runtime.h>
#include <hip/hip_bf16.h>
#include <math.h>

// Problem constants
#define V 32000
#define S 256
#define B 16
#define E 32
#define H 16
#define INV_KEEP (1.0f / 0.6f)
#define MR (S * B)      // 4096 hcat rows (sb = t*16 + b)
#define NVT (V / 16)    // 2000 v-tiles of 16

typedef __bf16 bf16x8 __attribute__((ext_vector_type(8)));
typedef float  f32x4  __attribute__((ext_vector_type(4)));

// dtype-generic load/store helpers --------------------------------------------
static __device__ __forceinline__ float ldf(const float* p, int i) { return p[i]; }
static __device__ __forceinline__ float ldf(const __hip_bfloat16* p, int i) { return __bfloat162float(p[i]); }
static __device__ __forceinline__ void stf(float* p, size_t i, float v) { p[i] = v; }
static __device__ __forceinline__ void stf(__hip_bfloat16* p, size_t i, float v) { p[i] = __float2bfloat16(v); }

// ---------------------------------------------------------------------------
// K0: dtype detector (unchanged).
// ---------------------------------------------------------------------------
__global__ void detect_kernel(const unsigned int* __restrict__ emb_words,
                              int* __restrict__ flag) {
    int lane = threadIdx.x;
    unsigned int w = emb_words[lane];
    unsigned int lo = w & 0xFFFFu;
    unsigned int ab = lo & 0x7FFFu;
    int hit = (ab == 0u) || (ab >= 0x3000u && ab <= 0x3E80u);
    unsigned long long m = __ballot(hit != 0);
    if (lane == 0) flag[0] = (__popcll(m) >= 32) ? 1 : 0;
}

// ---------------------------------------------------------------------------
// K1: pre[dir][t][b][i] = b_ih[i] + sum_e emb[tok[t,b]][e] * W_ih[e][i]
// (single launch, uniform runtime branch on flag for dtype)
// ---------------------------------------------------------------------------
template <typename T>
static __device__ __forceinline__ void precompute_body(
        const int* __restrict__ tok, const T* __restrict__ emb,
        const T* __restrict__ W_lr, const T* __restrict__ b_lr,
        const T* __restrict__ W_rl, const T* __restrict__ b_rl,
        float* __restrict__ pre) {
    int id = blockIdx.x * blockDim.x + threadIdx.x;   // 2*S*B*H = 131072
    if (id >= 2 * S * B * H) return;
    int dir = id >> 16;
    int rem = id & 0xFFFF;
    int t = rem >> 8;
    int b = (rem >> 4) & 15;
    int i = rem & 15;
    const T* Wp = dir ? W_rl : W_lr;
    const T* bp = dir ? b_rl : b_lr;
    int tk = tok[t * B + b];
    const T* er = emb + (size_t)tk * E;
    float acc = ldf(bp, i);
#pragma unroll
    for (int e = 0; e < E; ++e)
        acc += ldf(er, e) * ldf(Wp, e * H + i);
    pre[id] = acc;
}

__global__ void precompute_u_kernel(const int* __restrict__ tok,
                                    const void* emb,
                                    const void* W_lr, const void* b_lr,
                                    const void* W_rl, const void* b_rl,
                                    float* __restrict__ pre,
                                    const int* __restrict__ flag) {
    if (flag[0])
        precompute_body<__hip_bfloat16>(tok, (const __hip_bfloat16*)emb,
            (const __hip_bfloat16*)W_lr, (const __hip_bfloat16*)b_lr,
            (const __hip_bfloat16*)W_rl, (const __hip_bfloat16*)b_rl, pre);
    else
        precompute_body<float>(tok, (const float*)emb,
            (const float*)W_lr, (const float*)b_lr,
            (const float*)W_rl, (const float*)b_rl, pre);
}

// ---------------------------------------------------------------------------
// K2: sequential scans (proven round-3 structure; now single launch).
// ---------------------------------------------------------------------------
template <int J>
static __device__ __forceinline__ float grp_bcast(float h) {
#if __has_builtin(__builtin_amdgcn_ds_swizzle)
    // BitMode: offset = (xor<<10)|(or<<5)|and; lane' = (lane & 0x10) | J
    return __uint_as_float(__builtin_amdgcn_ds_swizzle(
        __float_as_uint(h), (J << 5) | 0x10));
#else
    int lane = threadIdx.x & 63;
    return __shfl(h, (lane & ~15) | J, 64);
#endif
}
static __device__ __forceinline__ float fast_rcp(float x) {
#if __has_builtin(__builtin_amdgcn_rcpf)
    return __builtin_amdgcn_rcpf(x);
#else
    return 1.f / x;
#endif
}
static __device__ __forceinline__ float fast_tanh(float x) {
    x = fminf(fmaxf(x, -15.f), 15.f);
    float e = __expf(2.f * x);
    return 1.f - 2.f * fast_rcp(e + 1.f);
}

template <typename T>
static __device__ __forceinline__ void scan_body(
        const float* __restrict__ pre,
        const T* __restrict__ mask_lr, const T* __restrict__ mask_rl,
        const T* __restrict__ W_lr, const T* __restrict__ W_rl,
        const T* __restrict__ h0, float* __restrict__ sarr) {
    int dir = blockIdx.x;
    int tid = threadIdx.x;     // 0..255
    int b = tid >> 4;
    int i = tid & 15;
    const T* Wp = dir ? W_rl : W_lr;
    const T* mk = dir ? mask_rl : mask_lr;
    float wh[H];
#pragma unroll
    for (int j = 0; j < H; ++j) wh[j] = ldf(Wp, (E + j) * H + i);
    float h = ldf(h0, i);
    const float* pred = pre + dir * (S * B * H);
    float* sd = sarr + dir * (S * B * H);

    int base = b * 16 + i;
    int step = dir ? -256 : 256;
    int idx = (dir ? (S - 1) * 256 : 0) + base;

    float pA = pred[idx];
    float mA = ldf(mk, idx) * INV_KEEP;
    float pB = pred[idx + step];
    float mB = ldf(mk, idx + step) * INV_KEEP;

    for (int k = 0; k < S; ++k) {
        float pN = 0.f, mN = 0.f;
        if (k + 2 < S) {
            int idn = idx + 2 * step;
            pN = pred[idn];
            mN = ldf(mk, idn) * INV_KEEP;
        }
        float s0 = grp_bcast<0>(h) * wh[0];
        s0 += grp_bcast<1>(h) * wh[1];
        s0 += grp_bcast<2>(h) * wh[2];
        s0 += grp_bcast<3>(h) * wh[3];
        float s1 = grp_bcast<4>(h) * wh[4];
        s1 += grp_bcast<5>(h) * wh[5];
        s1 += grp_bcast<6>(h) * wh[6];
        s1 += grp_bcast<7>(h) * wh[7];
        float s2 = grp_bcast<8>(h) * wh[8];
        s2 += grp_bcast<9>(h) * wh[9];
        s2 += grp_bcast<10>(h) * wh[10];
        s2 += grp_bcast<11>(h) * wh[11];
        float s3 = grp_bcast<12>(h) * wh[12];
        s3 += grp_bcast<13>(h) * wh[13];
        s3 += grp_bcast<14>(h) * wh[14];
        s3 += grp_bcast<15>(h) * wh[15];
        float acc = pA + ((s0 + s1) + (s2 + s3));
        h = fast_tanh(acc) * mA;
        sd[idx] = h;
        pA = pB; mA = mB; pB = pN; mB = mN;
        idx += step;
    }
}

__global__ void scan_u_kernel(const float* __restrict__ pre,
                              const void* mask_lr, const void* mask_rl,
                              const void* W_lr, const void* W_rl,
                              const void* h0, float* __restrict__ sarr,
                              const int* __restrict__ flag) {
    if (flag[0])
        scan_body<__hip_bfloat16>(pre, (const __hip_bfloat16*)mask_lr,
            (const __hip_bfloat16*)mask_rl, (const __hip_bfloat16*)W_lr,
            (const __hip_bfloat16*)W_rl, (const __hip_bfloat16*)h0, sarr);
    else
        scan_body<float>(pre, (const float*)mask_lr, (const float*)mask_rl,
            (const float*)W_lr, (const float*)W_rl, (const float*)h0, sarr);
}

// ---------------------------------------------------------------------------
// K3: pack hcat rows into bf16 hi/lo split, MFMA A-frag friendly layout.
// ---------------------------------------------------------------------------
template <typename T>
static __device__ __forceinline__ void pack_body(
        const float* __restrict__ sarr, const T* __restrict__ h0,
        __bf16* __restrict__ hi, __bf16* __restrict__ lo) {
    int id = blockIdx.x * blockDim.x + threadIdx.x;  // row*32 + k, 131072 total
    int k = id & 31;
    int row = id >> 5;
    int t = row >> 4, b = row & 15;
    const float* s0 = sarr;
    const float* s1 = sarr + S * B * H;
    float v;
    if (k < H)
        v = (t == 0) ? ldf(h0, k) : s0[(t - 1) * 256 + b * 16 + k];
    else
        v = (t == S - 1) ? ldf(h0, k - H) : s1[(t + 1) * 256 + b * 16 + (k - H)];
    __bf16 h = (__bf16)v;
    hi[id] = h;
    lo[id] = (__bf16)(v - (float)h);
}

__global__ void pack_u_kernel(const float* __restrict__ sarr, const void* h0,
                              __bf16* __restrict__ hi, __bf16* __restrict__ lo,
                              const int* __restrict__ flag) {
    if (flag[0]) pack_body<__hip_bfloat16>(sarr, (const __hip_bfloat16*)h0, hi, lo);
    else         pack_body<float>(sarr, (const float*)h0, hi, lo);
}

__global__ void zero_kernel(float* __restrict__ se) {
    int i = blockIdx.x * 256 + threadIdx.x;
    if (i < MR) se[i] = 0.f;
}

// ---------------------------------------------------------------------------
// K3b: pre-pack W_ho into MFMA-B-fragment-major bf16 hi/lo planes + fp32 bias.
// Also zeroes se (dedicated workspace region, no alias hazard).
// ---------------------------------------------------------------------------
template <typename T>
static __device__ __forceinline__ void wpack_body(
        const T* __restrict__ W_ho, const T* __restrict__ b_ho,
        __bf16* __restrict__ wph, __bf16* __restrict__ wpl,
        float* __restrict__ bsf) {
    int id = blockIdx.x * blockDim.x + threadIdx.x;  // 160000 total
    if (id < NVT * 64) {
        int c = id & 15, g = (id >> 4) & 3, vt = id >> 6;
        int v = vt * 16 + c;
        bf16x8 h8, l8;
#pragma unroll
        for (int j = 0; j < 8; ++j) {
            float w = ldf(W_ho, (size_t)(g * 8 + j) * V + v);
            __bf16 wh = (__bf16)w;
            h8[j] = wh;
            l8[j] = (__bf16)(w - (float)wh);
        }
        *(bf16x8*)(wph + (size_t)id * 8) = h8;
        *(bf16x8*)(wpl + (size_t)id * 8) = l8;
    } else {
        int v = id - NVT * 64;
        if (v < V) bsf[v] = ldf(b_ho, v);
    }
}

__global__ void wpack_u_kernel(const void* W_ho, const void* b_ho,
                               __bf16* __restrict__ wph, __bf16* __restrict__ wpl,
                               float* __restrict__ bsf, float* __restrict__ se,
                               const int* __restrict__ flag) {
    int id = blockIdx.x * blockDim.x + threadIdx.x;
    if (id < MR) se[id] = 0.f;
    if (flag[0])
        wpack_body<__hip_bfloat16>((const __hip_bfloat16*)W_ho,
                                   (const __hip_bfloat16*)b_ho, wph, wpl, bsf);
    else
        wpack_body<float>((const float*)W_ho, (const float*)b_ho, wph, wpl, bsf);
}

// ---------------------------------------------------------------------------
// K4p: sum-exp pass, packed-W (dtype-free, single launch). Unchanged math.
// ---------------------------------------------------------------------------
__global__ __launch_bounds__(256) void lse_packed_kernel(
        const __bf16* __restrict__ hi, const __bf16* __restrict__ lo,
        const __bf16* __restrict__ wph, const __bf16* __restrict__ wpl,
        const float* __restrict__ bsf,
        float* __restrict__ se) {
    int sbt = blockIdx.x >> 3;        // 0..255
    int vch = blockIdx.x & 7;         // 0..7
    int wave = threadIdx.x >> 6;
    int l = threadIdx.x & 63;
    int c = l & 15, g = l >> 4;
    int aoff = (sbt * 16 + c) * 32 + g * 8;
    bf16x8 ah = *(const bf16x8*)(hi + aoff);
    bf16x8 al = *(const bf16x8*)(lo + aoff);
    float part[4] = {0.f, 0.f, 0.f, 0.f};
    int vt_end = (vch + 1) * (NVT / 8);
    for (int vt = vch * (NVT / 8) + wave; vt < vt_end; vt += 4) {
        int woff = ((vt * 4 + g) * 16 + c) * 8;
        bf16x8 bh = *(const bf16x8*)(wph + woff);
        bf16x8 bl = *(const bf16x8*)(wpl + woff);
        f32x4 acc = {0.f, 0.f, 0.f, 0.f};
        acc = __builtin_amdgcn_mfma_f32_16x16x32_bf16(ah, bh, acc, 0, 0, 0);
        acc = __builtin_amdgcn_mfma_f32_16x16x32_bf16(al, bh, acc, 0, 0, 0);
        acc = __builtin_amdgcn_mfma_f32_16x16x32_bf16(ah, bl, acc, 0, 0, 0);
        float bb = bsf[vt * 16 + c];
#pragma unroll
        for (int r = 0; r < 4; ++r) part[r] += __expf(acc[r] + bb);
    }
#pragma unroll
    for (int r = 0; r < 4; ++r) {
        float p = part[r];
        p += __shfl_xor(p, 1, 64);
        p += __shfl_xor(p, 2, 64);
        p += __shfl_xor(p, 4, 64);
        p += __shfl_xor(p, 8, 64);
        if (c == 0) atomicAdd(&se[sbt * 16 + g * 4 + r], p);
    }
}

__global__ void log_kernel(float* __restrict__ se) {
    int i = blockIdx.x * 256 + threadIdx.x;
    if (i < MR) se[i] = logf(se[i]);
}

// ---------------------------------------------------------------------------
// K5p: write pass, 4-v-tile blocks. Block = (v-quad 0..499, sb-chunk 0..3).
// B-frags for 64 vocab columns loaded once (8x16B), reused across 64 sb-tiles.
// Per row, a 16-lane group writes 4x64B = 256B contiguous fp32 (2 full cache
// lines; no cross-block line sharing) / 128B bf16 (1 full line). 4 independent
// MFMA chains per iteration give ILP. Single launch, uniform dtype branch.
// ---------------------------------------------------------------------------
template <typename OT>
static __device__ __forceinline__ void write_body(
        const __bf16* __restrict__ hi, const __bf16* __restrict__ lo,
        const __bf16* __restrict__ wph, const __bf16* __restrict__ wpl,
        const float* __restrict__ bsf, const float* __restrict__ lse,
        OT* __restrict__ out) {
    int vq = blockIdx.x >> 2;   // 0..499 (64 vocab columns each)
    int sc = blockIdx.x & 3;    // sb-tile chunk of 64
    int l = threadIdx.x;
    int c = l & 15, g = l >> 4;
    int vt0 = vq * 4;
    bf16x8 bh0, bl0, bh1, bl1, bh2, bl2, bh3, bl3;
    float bb0, bb1, bb2, bb3;
    {
        int w0 = (((vt0 + 0) * 4 + g) * 16 + c) * 8;
        int w1 = (((vt0 + 1) * 4 + g) * 16 + c) * 8;
        int w2 = (((vt0 + 2) * 4 + g) * 16 + c) * 8;
        int w3 = (((vt0 + 3) * 4 + g) * 16 + c) * 8;
        bh0 = *(const bf16x8*)(wph + w0); bl0 = *(const bf16x8*)(wpl + w0);
        bh1 = *(const bf16x8*)(wph + w1); bl1 = *(const bf16x8*)(wpl + w1);
        bh2 = *(const bf16x8*)(wph + w2); bl2 = *(const bf16x8*)(wpl + w2);
        bh3 = *(const bf16x8*)(wph + w3); bl3 = *(const bf16x8*)(wpl + w3);
        bb0 = bsf[(vt0 + 0) * 16 + c];
        bb1 = bsf[(vt0 + 1) * 16 + c];
        bb2 = bsf[(vt0 + 2) * 16 + c];
        bb3 = bsf[(vt0 + 3) * 16 + c];
    }
    int sb_end = sc * 64 + 64;
    for (int sbt = sc * 64; sbt < sb_end; ++sbt) {
        int aoff = (sbt * 16 + c) * 32 + g * 8;
        bf16x8 ah = *(const bf16x8*)(hi + aoff);
        bf16x8 al = *(const bf16x8*)(lo + aoff);
        f32x4 a0 = {0.f, 0.f, 0.f, 0.f}, a1 = a0, a2 = a0, a3 = a0;
        a0 = __builtin_amdgcn_mfma_f32_16x16x32_bf16(ah, bh0, a0, 0, 0, 0);
        a1 = __builtin_amdgcn_mfma_f32_16x16x32_bf16(ah, bh1, a1, 0, 0, 0);
        a2 = __builtin_amdgcn_mfma_f32_16x16x32_bf16(ah, bh2, a2, 0, 0, 0);
        a3 = __builtin_amdgcn_mfma_f32_16x16x32_bf16(ah, bh3, a3, 0, 0, 0);
        a0 = __builtin_amdgcn_mfma_f32_16x16x32_bf16(al, bh0, a0, 0, 0, 0);
        a1 = __builtin_amdgcn_mfma_f32_16x16x32_bf16(al, bh1, a1, 0, 0, 0);
        a2 = __builtin_amdgcn_mfma_f32_16x16x32_bf16(al, bh2, a2, 0, 0, 0);
        a3 = __builtin_amdgcn_mfma_f32_16x16x32_bf16(al, bh3, a3, 0, 0, 0);
        a0 = __builtin_amdgcn_mfma_f32_16x16x32_bf16(ah, bl0, a0, 0, 0, 0);
        a1 = __builtin_amdgcn_mfma_f32_16x16x32_bf16(ah, bl1, a1, 0, 0, 0);
        a2 = __builtin_amdgcn_mfma_f32_16x16x32_bf16(ah, bl2, a2, 0, 0, 0);
        a3 = __builtin_amdgcn_mfma_f32_16x16x32_bf16(ah, bl3, a3, 0, 0, 0);
#pragma unroll
        for (int r = 0; r < 4; ++r) {
            int row = sbt * 16 + g * 4 + r;
            float ls = lse[row];
            size_t base = (size_t)row * V + vt0 * 16 + c;
            stf(out, base,      a0[r] + bb0 - ls);
            stf(out, base + 16, a1[r] + bb1 - ls);
            stf(out, base + 32, a2[r] + bb2 - ls);
            stf(out, base + 48, a3[r] + bb3 - ls);
        }
    }
}

__global__ __launch_bounds__(64) void write_u_kernel(
        const __bf16* __restrict__ hi, const __bf16* __restrict__ lo,
        const __bf16* __restrict__ wph, const __bf16* __restrict__ wpl,
        const float* __restrict__ bsf, const float* __restrict__ lse,
        void* out, const int* __restrict__ flag) {
    if (flag[0])
        write_body<__hip_bfloat16>(hi, lo, wph, wpl, bsf, lse, (__hip_bfloat16*)out);
    else
        write_body<float>(hi, lo, wph, wpl, bsf, lse, (float*)out);
}

// ---------------------------------------------------------------------------
// Fallback (ws too small for packed W): round-1-proven lse/write, dual-launch.
// ---------------------------------------------------------------------------
template <typename T>
__global__ __launch_bounds__(256) void lse_kernel(
        const __bf16* __restrict__ hi, const __bf16* __restrict__ lo,
        const T* __restrict__ W_ho, const T* __restrict__ b_ho,
        float* __restrict__ se,
        const int* __restrict__ flag, int want) {
    if (flag[0] != want) return;
    int sbt = blockIdx.x >> 3;
    int vch = blockIdx.x & 7;
    int wave = threadIdx.x >> 6;
    int l = threadIdx.x & 63;
    int c = l & 15, g = l >> 4;
    int aoff = (sbt * 16 + c) * 32 + g * 8;
    bf16x8 ah = *(const bf16x8*)(hi + aoff);
    bf16x8 al = *(const bf16x8*)(lo + aoff);
    float part[4] = {0.f, 0.f, 0.f, 0.f};
    int vt_end = (vch + 1) * (NVT / 8);
    for (int vt = vch * (NVT / 8) + wave; vt < vt_end; vt += 4) {
        int v0 = vt * 16;
        const T* wp = W_ho + (g * 8) * V + v0 + c;
        bf16x8 bh, bl;
#pragma unroll
        for (int j = 0; j < 8; ++j) {
            float w = ldf(wp, j * V);
            __bf16 wh = (__bf16)w;
            bh[j] = wh;
            bl[j] = (__bf16)(w - (float)wh);
        }
        f32x4 acc = {0.f, 0.f, 0.f, 0.f};
        acc = __builtin_amdgcn_mfma_f32_16x16x32_bf16(ah, bh, acc, 0, 0, 0);
        acc = __builtin_amdgcn_mfma_f32_16x16x32_bf16(al, bh, acc, 0, 0, 0);
        acc = __builtin_amdgcn_mfma_f32_16x16x32_bf16(ah, bl, acc, 0, 0, 0);
        float bb = ldf(b_ho, v0 + c);
#pragma unroll
        for (int r = 0; r < 4; ++r) part[r] += __expf(acc[r] + bb);
    }
#pragma unroll
    for (int r = 0; r < 4; ++r) {
        float p = part[r];
        p += __shfl_xor(p, 1, 64);
        p += __shfl_xor(p, 2, 64);
        p += __shfl_xor(p, 4, 64);
        p += __shfl_xor(p, 8, 64);
        if (c == 0) atomicAdd(&se[sbt * 16 + g * 4 + r], p);
    }
}

template <typename T>
__global__ __launch_bounds__(64) void write_kernel(
        const __bf16* __restrict__ hi, const __bf16* __restrict__ lo,
        const T* __restrict__ W_ho, const T* __restrict__ b_ho,
        const float* __restrict__ lse, T* __restrict__ out,
        const int* __restrict__ flag, int want) {
    if (flag[0] != want) return;
    int vt = blockIdx.x >> 2;
    int sc = blockIdx.x & 3;
    int l = threadIdx.x;
    int c = l & 15, g = l >> 4;
    int v0 = vt * 16;
    const T* wp = W_ho + (g * 8) * V + v0 + c;
    bf16x8 bh, bl;
#pragma unroll
    for (int j = 0; j < 8; ++j) {
        float w = ldf(wp, j * V);
        __bf16 wh = (__bf16)w;
        bh[j] = wh;
        bl[j] = (__bf16)(w - (float)wh);
    }
    float bb = ldf(b_ho, v0 + c);
    int sb_end = sc * 64 + 64;
    for (int sbt = sc * 64; sbt < sb_end; ++sbt) {
        int aoff = (sbt * 16 + c) * 32 + g * 8;
        bf16x8 ah = *(const bf16x8*)(hi + aoff);
        bf16x8 al = *(const bf16x8*)(lo + aoff);
        f32x4 acc = {0.f, 0.f, 0.f, 0.f};
        acc = __builtin_amdgcn_mfma_f32_16x16x32_bf16(ah, bh, acc, 0, 0, 0);
        acc = __builtin_amdgcn_mfma_f32_16x16x32_bf16(al, bh, acc, 0, 0, 0);
        acc = __builtin_amdgcn_mfma_f32_16x16x32_bf16(ah, bl, acc, 0, 0, 0);
#pragma unroll
        for (int r = 0; r < 4; ++r) {
            int row = sbt * 16 + g * 4 + r;
            stf(out, (size_t)row * V + v0 + c, acc[r] + bb - lse[row]);
        }
    }
}

// ---------------------------------------------------------------------------
// Workspace layout (bytes):
//   [0      .. 512K)   pre (fp32) -> reused as hcb_hi (256K) + hcb_lo (256K)
//   [512K   .. 1M)     sarr (fp32)
//   [1M]               flag
//   -- packed path only (requires ws_size >= 8MB) --
//   [2M .. 2M+2,048,000)  wph
//   [4M .. 4M+2,048,000)  wpl
//   [6M .. 6M+128K)       bsf (fp32 bias)
//   [7M .. 7M+16K)        se (sum-exp / lse) -- own region, zeroed in wpack
// Fallback path keeps se aliased to sarr head with post-pack zeroing.
// ---------------------------------------------------------------------------
extern "C" void kernel_launch(void* const* d_in, const int* in_sizes, int n_in,
                              void* d_out, int out_size, void* d_ws, size_t ws_size,
                              hipStream_t stream) {
    const int* tok = (const int*)d_in[0];

    char* wsb      = (char*)d_ws;
    float* pre     = (float*)wsb;
    float* sarr    = (float*)(wsb + (512u << 10));
    __bf16* hcb_hi = (__bf16*)wsb;
    __bf16* hcb_lo = (__bf16*)(wsb + (256u << 10));
    int*   flag    = (int*)(wsb + (1u << 20));
    __bf16* wph    = (__bf16*)(wsb + (2u << 20));
    __bf16* wpl    = (__bf16*)(wsb + (4u << 20));
    float* bsf     = (float*)(wsb + (6u << 20));
    float* sep     = (float*)(wsb + (7u << 20));   // packed-path se
    const bool packed = ws_size >= ((size_t)8u << 20);

    detect_kernel<<<1, 64, 0, stream>>>((const unsigned int*)d_in[3], flag);

    if (packed) {
        // single-launch unified pipeline
        wpack_u_kernel<<<625, 256, 0, stream>>>(d_in[8], d_in[9], wph, wpl, bsf, sep, flag);
        precompute_u_kernel<<<512, 256, 0, stream>>>(tok, d_in[3], d_in[4], d_in[5],
                                                     d_in[6], d_in[7], pre, flag);
        scan_u_kernel<<<2, 256, 0, stream>>>(pre, d_in[1], d_in[2], d_in[4],
                                             d_in[6], d_in[10], sarr, flag);
        pack_u_kernel<<<512, 256, 0, stream>>>(sarr, d_in[10], hcb_hi, hcb_lo, flag);
        lse_packed_kernel<<<2048, 256, 0, stream>>>(hcb_hi, hcb_lo, wph, wpl, bsf, sep);
        log_kernel<<<16, 256, 0, stream>>>(sep);
        write_u_kernel<<<2000, 64, 0, stream>>>(hcb_hi, hcb_lo, wph, wpl, bsf, sep,
                                                d_out, flag);
    } else {
        float* se = sarr;   // aliases sarr head; zeroed after pack reads sarr
        precompute_u_kernel<<<512, 256, 0, stream>>>(tok, d_in[3], d_in[4], d_in[5],
                                                     d_in[6], d_in[7], pre, flag);
        scan_u_kernel<<<2, 256, 0, stream>>>(pre, d_in[1], d_in[2], d_in[4],
                                             d_in[6], d_in[10], sarr, flag);
        pack_u_kernel<<<512, 256, 0, stream>>>(sarr, d_in[10], hcb_hi, hcb_lo, flag);
        zero_kernel<<<16, 256, 0, stream>>>(se);
        lse_kernel<float><<<2048, 256, 0, stream>>>(
            hcb_hi, hcb_lo, (const float*)d_in[8], (const float*)d_in[9], se, flag, 0);
        lse_kernel<__hip_bfloat16><<<2048, 256, 0, stream>>>(
            hcb_hi, hcb_lo, (const __hip_bfloat16*)d_in[8], (const __hip_bfloat16*)d_in[9], se, flag, 1);
        log_kernel<<<16, 256, 0, stream>>>(se);
        write_kernel<float><<<8000, 64, 0, stream>>>(
            hcb_hi, hcb_lo, (const float*)d_in[8], (const float*)d_in[9], se, (float*)d_out, flag, 0);
        write_kernel<__hip_bfloat16><<<8000, 64, 0, stream>>>(
            hcb_hi, hcb_lo, (const __hip_bfloat16*)d_in[8], (const __hip_bfloat16*)d_in[9], se, (__hip_bfloat16*)d_out, flag, 1);
    }
}